// Round 1
// baseline (56.058 us; speedup 1.0000x reference)
//
#include <hip/hip_runtime.h>
#include <hip/hip_bf16.h>
#include <math.h>

// Problem constants
// B=4, N=512, T=288, L=128
#define NB 4
#define NN 512
#define NT 288
#define NL 128

// ---------------------------------------------------------------------------
// Kernel A: fused  x -> x1,x2 (leaky(x·W^T+b)) -> S1=x1·Wp_a^T+bp, S2=x2·Wp_b^T
// plus per-row dots  A[bn]=0.6*dot(S1,Wb)+bb,  C[bn]=0.6*dot(S2,Wb)
// One block = 8 consecutive bn rows. 256 blocks x 256 threads.
// S12 layout: [bn][256] where cols 0..127 = S1 (incl bp), cols 128..255 = S2.
// ---------------------------------------------------------------------------
__global__ __launch_bounds__(256) void kA(
    const float* __restrict__ x,   // [2048][288]
    const float* __restrict__ W1,  // [128][288]
    const float* __restrict__ b1,  // [128]
    const float* __restrict__ W2,  // [128][288]
    const float* __restrict__ b2,  // [128]
    const float* __restrict__ Wp,  // [128][256]
    const float* __restrict__ bp,  // [128]
    const float* __restrict__ Wb,  // [128]
    const float* __restrict__ bb,  // [1]
    float* __restrict__ S12,       // [2048][256]
    float* __restrict__ Aarr,      // [2048]
    float* __restrict__ Carr)      // [2048]
{
    __shared__ __align__(16) float xs[8 * NT];    // 8 x rows; later aliased as s12s[8][257]
    __shared__ __align__(16) float x12s[8 * 256]; // 8 rows of [x1|x2]

    const int t = threadIdx.x;
    const int bn0 = blockIdx.x * 8;

    // stage 8 x-rows (8*288 floats = 576 float4)
    for (int q = 0; q < 3; ++q) {
        int idx = q * 256 + t;
        if (idx < 576) {
            int row = idx / 72, c4 = idx % 72;
            *(float4*)&xs[row * NT + c4 * 4] =
                *(const float4*)&x[(size_t)(bn0 + row) * NT + c4 * 4];
        }
    }
    __syncthreads();

    // ---- G1: thread t computes column t of [x1|x2] for all 8 rows ----
    const float* wrow = (t < 128) ? (W1 + t * NT) : (W2 + (t - 128) * NT);
    const float bias1 = (t < 128) ? b1[t] : b2[t - 128];
    float acc[8];
#pragma unroll
    for (int n = 0; n < 8; ++n) acc[n] = 0.0f;

    for (int k = 0; k < NT; k += 4) {
        float4 w = *(const float4*)(wrow + k);
#pragma unroll
        for (int n = 0; n < 8; ++n) {
            float4 xv = *(const float4*)&xs[n * NT + k];
            acc[n] = fmaf(w.x, xv.x, acc[n]);
            acc[n] = fmaf(w.y, xv.y, acc[n]);
            acc[n] = fmaf(w.z, xv.z, acc[n]);
            acc[n] = fmaf(w.w, xv.w, acc[n]);
        }
    }
#pragma unroll
    for (int n = 0; n < 8; ++n) {
        float v = acc[n] + bias1;
        x12s[n * 256 + t] = fmaxf(v, 0.2f * v);   // leaky relu
    }
    __syncthreads();

    // ---- G2: thread t computes column t of [S1|S2] for all 8 rows ----
    const float* wprow = (t < 128) ? (Wp + t * 256) : (Wp + (t - 128) * 256 + 128);
    const int koff = (t < 128) ? 0 : 128;
    const float bias2 = (t < 128) ? bp[t] : 0.0f;

    float acc2[8];
#pragma unroll
    for (int n = 0; n < 8; ++n) acc2[n] = 0.0f;

    for (int k = 0; k < 128; k += 4) {
        float4 w = *(const float4*)(wprow + k);
#pragma unroll
        for (int n = 0; n < 8; ++n) {
            float4 xv = *(const float4*)&x12s[n * 256 + koff + k];
            acc2[n] = fmaf(w.x, xv.x, acc2[n]);
            acc2[n] = fmaf(w.y, xv.y, acc2[n]);
            acc2[n] = fmaf(w.z, xv.z, acc2[n]);
            acc2[n] = fmaf(w.w, xv.w, acc2[n]);
        }
    }

    // write S12 to global and to LDS (alias xs, stride 257 to dodge bank conflicts)
    float* s12s = xs;   // xs no longer read after the barrier above
#pragma unroll
    for (int n = 0; n < 8; ++n) {
        float sv = acc2[n] + bias2;
        S12[(size_t)(bn0 + n) * 256 + t] = sv;
        s12s[n * 257 + t] = sv;
    }
    __syncthreads();

    // ---- per-row dots with Wb (16 serial dots, threads 0..15) ----
    if (t < 16) {
        int n = t & 7;
        int isC = t >> 3;
        int base = isC ? 128 : 0;
        float sum = 0.0f;
        for (int j = 0; j < 128; ++j)
            sum = fmaf(s12s[n * 257 + base + j], Wb[j], sum);
        if (isC) Carr[bn0 + n] = 0.6f * sum;
        else     Aarr[bn0 + n] = 0.6f * sum + bb[0];
    }
}

// ---------------------------------------------------------------------------
// Kernel B: pairwise |S1[i]+S2[j]| reduction + sigmoid, per b.
// grid (8,8,4) = (i-tile, j-tile, b). 64x64 output tile, 4x4 per thread.
// LDS tiles stored [l][i] with XOR swizzle  i ^ ((l>>2)&15)<<2  so the
// per-l ds_read_b128 of 4 consecutive i (and j) is bank-conflict-free.
// ---------------------------------------------------------------------------
__global__ __launch_bounds__(256) void kB(
    const float* __restrict__ S12,   // [2048][256]
    const float* __restrict__ Aarr,  // [2048]
    const float* __restrict__ Carr,  // [2048]
    const float* __restrict__ Wb,    // [128]
    float* __restrict__ PS4)         // [4][512][512] sigmoid(logits)
{
    __shared__ __align__(16) float S1t[128 * 64];
    __shared__ __align__(16) float S2t[128 * 64];

    const int t = threadIdx.x;
    const int bx = blockIdx.x, by = blockIdx.y, bz = blockIdx.z;
    const int ibn0 = bz * NN + bx * 64;
    const int jbn0 = bz * NN + by * 64;

    // stage both tiles (64 rows x 128 cols each), transposed+swizzled into LDS
#pragma unroll
    for (int q = 0; q < 8; ++q) {
        int idx = q * 256 + t;      // float4 index, 0..2047
        int row = idx >> 5;         // 0..63
        int c4 = idx & 31;          // 0..31  (col = c4*4)
        float4 v1 = *(const float4*)&S12[(size_t)(ibn0 + row) * 256 + c4 * 4];
        float4 v2 = *(const float4*)&S12[(size_t)(jbn0 + row) * 256 + 128 + c4 * 4];
        float a1[4] = {v1.x, v1.y, v1.z, v1.w};
        float a2[4] = {v2.x, v2.y, v2.z, v2.w};
#pragma unroll
        for (int d = 0; d < 4; ++d) {
            int l = c4 * 4 + d;
            int sw = ((l >> 2) & 15) << 2;
            S1t[l * 64 + (row ^ sw)] = a1[d];
            S2t[l * 64 + (row ^ sw)] = a2[d];
        }
    }
    __syncthreads();

    const int tx = t & 15, ty = t >> 4;
    const int i0 = ty * 4, j0 = tx * 4;

    float accv[16];
#pragma unroll
    for (int k = 0; k < 16; ++k) accv[k] = 0.0f;

    for (int l4 = 0; l4 < 32; ++l4) {
        const int sw = (l4 & 15) << 2;       // = ((l>>2)&15)<<2 for l = 4*l4+d
#pragma unroll
        for (int d = 0; d < 4; ++d) {
            const int l = l4 * 4 + d;
            float4 a = *(const float4*)&S1t[l * 64 + (i0 ^ sw)];
            float4 b = *(const float4*)&S2t[l * 64 + (j0 ^ sw)];
            float w = Wb[l];
            float ai[4] = {a.x, a.y, a.z, a.w};
            float bj[4] = {b.x, b.y, b.z, b.w};
#pragma unroll
            for (int ii = 0; ii < 4; ++ii) {
#pragma unroll
                for (int jj = 0; jj < 4; ++jj) {
                    float tv = ai[ii] + bj[jj];
                    accv[ii * 4 + jj] = fmaf(fabsf(tv), w, accv[ii * 4 + jj]);
                }
            }
        }
    }

    // epilogue: logits = A[i] + C[j] + 0.4*acc ; sigmoid ; store per-b
    float Av[4], Cv[4];
#pragma unroll
    for (int ii = 0; ii < 4; ++ii) Av[ii] = Aarr[ibn0 + i0 + ii];
#pragma unroll
    for (int jj = 0; jj < 4; ++jj) Cv[jj] = Carr[jbn0 + j0 + jj];

#pragma unroll
    for (int ii = 0; ii < 4; ++ii) {
        float4 o;
        float* op = (float*)&o;
#pragma unroll
        for (int jj = 0; jj < 4; ++jj) {
            float lg = Av[ii] + Cv[jj] + 0.4f * accv[ii * 4 + jj];
            op[jj] = 1.0f / (1.0f + expf(-lg));
        }
        *(float4*)&PS4[(size_t)bz * (NN * NN) +
                       (size_t)(bx * 64 + i0 + ii) * NN + by * 64 + j0] = o;
    }
}

// ---------------------------------------------------------------------------
// Kernel F: p = mean_b sigmoid ; zero diagonal ; logit clamp ; noise logistic ;
// final sigmoid with temperature 0.2.  One float4 per thread.
// ---------------------------------------------------------------------------
__global__ __launch_bounds__(256) void kF(
    const float* __restrict__ PS4,    // [4][512][512]
    const float* __restrict__ noise,  // [512][512]
    float* __restrict__ out)          // [512][512]
{
    int g = blockIdx.x * 256 + threadIdx.x;   // float4 index 0..65535
    int f = g * 4;
    int i = f >> 9;
    int jbase = f & 511;

    float4 s0 = *(const float4*)&PS4[f];
    float4 s1 = *(const float4*)&PS4[262144 + f];
    float4 s2 = *(const float4*)&PS4[524288 + f];
    float4 s3 = *(const float4*)&PS4[786432 + f];
    float4 nz = *(const float4*)&noise[f];

    float ps[4] = {s0.x + s1.x + s2.x + s3.x,
                   s0.y + s1.y + s2.y + s3.y,
                   s0.z + s1.z + s2.z + s3.z,
                   s0.w + s1.w + s2.w + s3.w};
    float nv[4] = {nz.x, nz.y, nz.z, nz.w};

    float4 o;
    float* op = (float*)&o;
#pragma unroll
    for (int c = 0; c < 4; ++c) {
        float p = 0.25f * ps[c];
        if (jbase + c == i) p = 0.0f;
        float lp = logf(p + 1e-10f) - log1pf(-p + 1e-10f);
        lp = fminf(fmaxf(lp, -10.0f), 10.0f);
        float lgs = logf(nv[c]) - log1pf(-nv[c]);
        op[c] = 1.0f / (1.0f + expf(-(lp + lgs) * 5.0f));
    }
    *(float4*)&out[f] = o;
}

// ---------------------------------------------------------------------------
extern "C" void kernel_launch(void* const* d_in, const int* in_sizes, int n_in,
                              void* d_out, int out_size, void* d_ws, size_t ws_size,
                              hipStream_t stream) {
    const float* x     = (const float*)d_in[0];
    const float* W1    = (const float*)d_in[1];
    const float* b1    = (const float*)d_in[2];
    const float* W2    = (const float*)d_in[3];
    const float* b2    = (const float*)d_in[4];
    const float* Wp    = (const float*)d_in[5];
    const float* bp    = (const float*)d_in[6];
    const float* Wb    = (const float*)d_in[7];
    const float* bb    = (const float*)d_in[8];
    const float* noise = (const float*)d_in[9];

    float* ws   = (float*)d_ws;
    float* S12  = ws;                 // 2048*256       = 524288 floats
    float* Aarr = ws + 524288;        // 2048
    float* Carr = Aarr + 2048;        // 2048
    float* PS4  = Carr + 2048;        // 4*512*512      = 1048576 floats

    kA<<<256, 256, 0, stream>>>(x, W1, b1, W2, b2, Wp, bp, Wb, bb, S12, Aarr, Carr);
    kB<<<dim3(8, 8, 4), 256, 0, stream>>>(S12, Aarr, Carr, Wb, PS4);
    kF<<<256, 256, 0, stream>>>(PS4, noise, (float*)d_out);
}

// Round 2
// 44.819 us; speedup vs baseline: 1.2508x; 1.2508x over previous
//
#include <hip/hip_runtime.h>
#include <hip/hip_bf16.h>
#include <math.h>

// B=4, N=512, T=288, L=128
#define NB 4
#define NN 512
#define NT 288
#define NL 128

// ---------------------------------------------------------------------------
// Kernel A: fused  x -> x1,x2 (leaky(x·W^T+b)) -> S1=x1·Wp_a^T+bp, S2=x2·Wp_b^T
// plus per-row dots  A[bn]=0.6*dot(S1,Wb)+bb,  C[bn]=0.6*dot(S2,Wb)
// One block = 8 consecutive bn rows, 512 threads (thread halves split the K
// range of each GEMM stage; partials combined through LDS). 256 blocks.
// S12 layout: [bn][256], cols 0..127 = S1 (incl bp), cols 128..255 = S2.
// ---------------------------------------------------------------------------
__global__ __launch_bounds__(512) void kA(
    const float* __restrict__ x,   // [2048][288]
    const float* __restrict__ W1,  // [128][288]
    const float* __restrict__ b1,  // [128]
    const float* __restrict__ W2,  // [128][288]
    const float* __restrict__ b2,  // [128]
    const float* __restrict__ Wp,  // [128][256]
    const float* __restrict__ bp,  // [128]
    const float* __restrict__ Wb,  // [128]
    const float* __restrict__ bb,  // [1]
    float* __restrict__ S12,       // [2048][256]
    float* __restrict__ Aarr,      // [2048]
    float* __restrict__ Carr)      // [2048]
{
    __shared__ __align__(16) float xs[8 * NT];     // 8 x rows; later aliased s12s[8][257]
    __shared__ __align__(16) float x12s[8 * 256];  // 8 rows of [x1|x2]
    __shared__ __align__(16) float ph[8 * 256];    // high-half partials

    const int t = threadIdx.x;
    const int bn0 = blockIdx.x * 8;
    const int col = t & 255;
    const int kh = t >> 8;        // 0 = low K half, 1 = high K half

    // stage 8 x-rows (576 float4)
    for (int q = 0; q < 2; ++q) {
        int idx = q * 512 + t;
        if (idx < 576) {
            int row = idx / 72, c4 = idx % 72;
            *(float4*)&xs[row * NT + c4 * 4] =
                *(const float4*)&x[(size_t)(bn0 + row) * NT + c4 * 4];
        }
    }
    __syncthreads();

    // ---- G1: col of [x1|x2] for 8 rows; K=288 split 144/144 ----
    const float* wrow = ((col < 128) ? (W1 + col * NT) : (W2 + (col - 128) * NT))
                        + kh * 144;
    const float bias1 = (col < 128) ? b1[col] : b2[col - 128];
    const int kb1 = kh * 144;

    float acc[8];
#pragma unroll
    for (int n = 0; n < 8; ++n) acc[n] = 0.0f;

    for (int k = 0; k < 144; k += 4) {
        float4 w = *(const float4*)(wrow + k);
#pragma unroll
        for (int n = 0; n < 8; ++n) {
            float4 xv = *(const float4*)&xs[n * NT + kb1 + k];
            acc[n] = fmaf(w.x, xv.x, acc[n]);
            acc[n] = fmaf(w.y, xv.y, acc[n]);
            acc[n] = fmaf(w.z, xv.z, acc[n]);
            acc[n] = fmaf(w.w, xv.w, acc[n]);
        }
    }
    if (kh) {
#pragma unroll
        for (int n = 0; n < 8; ++n) ph[n * 256 + col] = acc[n];
    }
    __syncthreads();
    if (!kh) {
#pragma unroll
        for (int n = 0; n < 8; ++n) {
            float v = acc[n] + ph[n * 256 + col] + bias1;
            x12s[n * 256 + col] = fmaxf(v, 0.2f * v);   // leaky
        }
    }
    __syncthreads();

    // ---- G2: col of [S1|S2] for 8 rows; K=128 split 64/64 ----
    const int koff = (col < 128) ? 0 : 128;
    const float* wprow = ((col < 128) ? (Wp + col * 256) : (Wp + (col - 128) * 256 + 128))
                         + kh * 64;
    const float bias2 = (col < 128) ? bp[col] : 0.0f;
    const int kb2 = koff + kh * 64;

    float acc2[8];
#pragma unroll
    for (int n = 0; n < 8; ++n) acc2[n] = 0.0f;

    for (int k = 0; k < 64; k += 4) {
        float4 w = *(const float4*)(wprow + k);
#pragma unroll
        for (int n = 0; n < 8; ++n) {
            float4 xv = *(const float4*)&x12s[n * 256 + kb2 + k];
            acc2[n] = fmaf(w.x, xv.x, acc2[n]);
            acc2[n] = fmaf(w.y, xv.y, acc2[n]);
            acc2[n] = fmaf(w.z, xv.z, acc2[n]);
            acc2[n] = fmaf(w.w, xv.w, acc2[n]);
        }
    }
    if (kh) {
#pragma unroll
        for (int n = 0; n < 8; ++n) ph[n * 256 + col] = acc2[n];
    }
    __syncthreads();

    float* s12s = xs;   // alias: xs dead after G1
    if (!kh) {
#pragma unroll
        for (int n = 0; n < 8; ++n) {
            float sv = acc2[n] + ph[n * 256 + col] + bias2;
            S12[(size_t)(bn0 + n) * 256 + col] = sv;
            s12s[n * 257 + col] = sv;
        }
    }
    __syncthreads();

    // ---- per-row dots with Wb: 16 dots x 32 lanes each ----
    {
        int lane32 = t & 31;
        int n = (t >> 5) & 7;
        int isC = t >> 8;
        int base = isC ? 128 : 0;
        float sum = 0.0f;
#pragma unroll
        for (int s = 0; s < 4; ++s) {
            int j = lane32 + s * 32;
            sum = fmaf(s12s[n * 257 + base + j], Wb[j], sum);
        }
#pragma unroll
        for (int m = 16; m >= 1; m >>= 1)
            sum += __shfl_xor(sum, m, 32);
        if (lane32 == 0) {
            if (isC) Carr[bn0 + n] = 0.6f * sum;
            else     Aarr[bn0 + n] = 0.6f * sum + bb[0];
        }
    }
}

// ---------------------------------------------------------------------------
// Kernel B: pairwise  acc(i,j) = sum_l |S1[i][l]+S2[j][l]| * Wb[l]
// grid (8,8,4), 512 threads. 64x64 tile, 4x4 per (low) thread; thread halves
// split the l-range 64/64 and cross-reduce through LDS (aliased on S1t).
// LDS tiles stored [l][i] with XOR swizzle  i ^ (((l>>2)&15)<<2)  so both the
// staging writes and the per-l ds_read_b128 of 4 consecutive i/j behave.
// ---------------------------------------------------------------------------
__global__ __launch_bounds__(512) void kB(
    const float* __restrict__ S12,   // [2048][256]
    const float* __restrict__ Aarr,  // [2048]
    const float* __restrict__ Carr,  // [2048]
    const float* __restrict__ Wb,    // [128]
    float* __restrict__ PS4)         // [4][512][512] sigmoid(logits)
{
    __shared__ __align__(16) float S1t[128 * 64];
    __shared__ __align__(16) float S2t[128 * 64];
    __shared__ __align__(16) float wbs[128];

    const int t = threadIdx.x;
    const int bx = blockIdx.x, by = blockIdx.y, bz = blockIdx.z;
    const int ibn0 = bz * NN + bx * 64;
    const int jbn0 = bz * NN + by * 64;

    if (t < 32) *(float4*)&wbs[t * 4] = *(const float4*)&Wb[t * 4];

    // stage both tiles (64 rows x 128 cols), transposed+swizzled
#pragma unroll
    for (int q = 0; q < 4; ++q) {
        int idx = q * 512 + t;      // float4 index 0..2047
        int row = idx >> 5;         // 0..63
        int c4 = idx & 31;          // col = c4*4
        float4 v1 = *(const float4*)&S12[(size_t)(ibn0 + row) * 256 + c4 * 4];
        float4 v2 = *(const float4*)&S12[(size_t)(jbn0 + row) * 256 + 128 + c4 * 4];
        float a1[4] = {v1.x, v1.y, v1.z, v1.w};
        float a2[4] = {v2.x, v2.y, v2.z, v2.w};
#pragma unroll
        for (int d = 0; d < 4; ++d) {
            int l = c4 * 4 + d;
            int sw = ((l >> 2) & 15) << 2;
            S1t[l * 64 + (row ^ sw)] = a1[d];
            S2t[l * 64 + (row ^ sw)] = a2[d];
        }
    }
    __syncthreads();

    const int tid = t & 255;
    const int lh = t >> 8;                 // l-half
    const int tx = tid & 15, ty = tid >> 4;
    const int i0 = ty * 4, j0 = tx * 4;
    const int lbase = lh * 64;

    float accv[16];
#pragma unroll
    for (int k = 0; k < 16; ++k) accv[k] = 0.0f;

    for (int l4 = 0; l4 < 16; ++l4) {
        const int sw = l4 << 2;            // == ((l>>2)&15)<<2 for this l-range
        const int lrow = (lbase + l4 * 4) * 64;
        float4 wv = *(const float4*)&wbs[lbase + l4 * 4];
        const float wl[4] = {wv.x, wv.y, wv.z, wv.w};
#pragma unroll
        for (int d = 0; d < 4; ++d) {
            float4 a = *(const float4*)&S1t[lrow + d * 64 + (i0 ^ sw)];
            float4 b = *(const float4*)&S2t[lrow + d * 64 + (j0 ^ sw)];
            float w = wl[d];
            float ai[4] = {a.x, a.y, a.z, a.w};
            float bj[4] = {b.x, b.y, b.z, b.w};
#pragma unroll
            for (int ii = 0; ii < 4; ++ii)
#pragma unroll
                for (int jj = 0; jj < 4; ++jj) {
                    float tv = ai[ii] + bj[jj];
                    accv[ii * 4 + jj] = fmaf(fabsf(tv), w, accv[ii * 4 + jj]);
                }
        }
    }

    // cross-reduce the two l-halves through LDS (alias onto S1t)
    float* red = S1t;                      // 4096 floats = 16 KB
    __syncthreads();                       // everyone done reading tiles
    if (lh) {
#pragma unroll
        for (int q = 0; q < 4; ++q) {
            float4 v = {accv[4 * q], accv[4 * q + 1], accv[4 * q + 2], accv[4 * q + 3]};
            *(float4*)&red[q * 1024 + tid * 4] = v;
        }
    }
    __syncthreads();
    if (!lh) {
#pragma unroll
        for (int q = 0; q < 4; ++q) {
            float4 v = *(const float4*)&red[q * 1024 + tid * 4];
            accv[4 * q]     += v.x;
            accv[4 * q + 1] += v.y;
            accv[4 * q + 2] += v.z;
            accv[4 * q + 3] += v.w;
        }

        float Av[4], Cv[4];
#pragma unroll
        for (int ii = 0; ii < 4; ++ii) Av[ii] = Aarr[ibn0 + i0 + ii];
#pragma unroll
        for (int jj = 0; jj < 4; ++jj) Cv[jj] = Carr[jbn0 + j0 + jj];

#pragma unroll
        for (int ii = 0; ii < 4; ++ii) {
            float4 o;
            float* op = (float*)&o;
#pragma unroll
            for (int jj = 0; jj < 4; ++jj) {
                float lg = Av[ii] + Cv[jj] + 0.4f * accv[ii * 4 + jj];
                op[jj] = 1.0f / (1.0f + expf(-lg));
            }
            *(float4*)&PS4[(size_t)bz * (NN * NN) +
                           (size_t)(bx * 64 + i0 + ii) * NN + by * 64 + j0] = o;
        }
    }
}

// ---------------------------------------------------------------------------
// Kernel F: p = mean_b sigmoid ; zero diag ; logit clamp ; noise logistic ;
// final sigmoid (T=0.2). float2 per thread, 512 blocks x 256 threads.
// ---------------------------------------------------------------------------
__global__ __launch_bounds__(256) void kF(
    const float* __restrict__ PS4,    // [4][512][512]
    const float* __restrict__ noise,  // [512][512]
    float* __restrict__ out)          // [512][512]
{
    int g = blockIdx.x * 256 + threadIdx.x;   // float2 index 0..131071
    int f = g * 2;
    int i = f >> 9;
    int jbase = f & 511;

    float2 s0 = *(const float2*)&PS4[f];
    float2 s1 = *(const float2*)&PS4[262144 + f];
    float2 s2 = *(const float2*)&PS4[524288 + f];
    float2 s3 = *(const float2*)&PS4[786432 + f];
    float2 nz = *(const float2*)&noise[f];

    float ps[2] = {s0.x + s1.x + s2.x + s3.x,
                   s0.y + s1.y + s2.y + s3.y};
    float nv[2] = {nz.x, nz.y};

    float2 o;
    float* op = (float*)&o;
#pragma unroll
    for (int c = 0; c < 2; ++c) {
        float p = 0.25f * ps[c];
        if (jbase + c == i) p = 0.0f;
        float lp = logf(p + 1e-10f) - log1pf(-p + 1e-10f);
        lp = fminf(fmaxf(lp, -10.0f), 10.0f);
        float lgs = logf(nv[c]) - log1pf(-nv[c]);
        op[c] = 1.0f / (1.0f + expf(-(lp + lgs) * 5.0f));
    }
    *(float2*)&out[f] = o;
}

// ---------------------------------------------------------------------------
extern "C" void kernel_launch(void* const* d_in, const int* in_sizes, int n_in,
                              void* d_out, int out_size, void* d_ws, size_t ws_size,
                              hipStream_t stream) {
    const float* x     = (const float*)d_in[0];
    const float* W1    = (const float*)d_in[1];
    const float* b1    = (const float*)d_in[2];
    const float* W2    = (const float*)d_in[3];
    const float* b2    = (const float*)d_in[4];
    const float* Wp    = (const float*)d_in[5];
    const float* bp    = (const float*)d_in[6];
    const float* Wb    = (const float*)d_in[7];
    const float* bb    = (const float*)d_in[8];
    const float* noise = (const float*)d_in[9];

    float* ws   = (float*)d_ws;
    float* S12  = ws;                 // 524288 floats
    float* Aarr = ws + 524288;        // 2048
    float* Carr = Aarr + 2048;        // 2048
    float* PS4  = Carr + 2048;        // 1048576 floats

    kA<<<256, 512, 0, stream>>>(x, W1, b1, W2, b2, Wp, bp, Wb, bb, S12, Aarr, Carr);
    kB<<<dim3(8, 8, 4), 512, 0, stream>>>(S12, Aarr, Carr, Wb, PS4);
    kF<<<512, 256, 0, stream>>>(PS4, noise, (float*)d_out);
}